// Round 6
// baseline (2931.585 us; speedup 1.0000x reference)
//
#include <hip/hip_runtime.h>

#define N_NODES 50000
#define N_EDGES 800000
#define BKN 64                      // nodes per bucket: bucket = dst >> 6
#define NBUCK 782                   // ceil(50000/64)
#define ASTR 132                    // LDS acc row stride (floats): 16B-aligned + bank rotation
#define EPB 4096                    // edges per stripe-block in pass A
#define NSTRIPE ((N_EDGES + EPB - 1) / EPB)  // 196

typedef __attribute__((ext_vector_type(8))) short short8;
typedef __attribute__((ext_vector_type(4))) float float4v;

__device__ inline unsigned short f2bf(float f) {
    unsigned u = __float_as_uint(f);
    unsigned r = u + 0x7fff + ((u >> 16) & 1);
    return (unsigned short)(r >> 16);
}
__device__ inline float bf2f(unsigned short h) {
    return __uint_as_float(((unsigned)h) << 16);
}

// ---------------- fused: bucket histogram (196 blocks) + weight split (288) ----------

__global__ void __launch_bounds__(256) fused_hist_prep(
    const int* __restrict__ dst, int* __restrict__ bcnt, const float* __restrict__ fcW,
    const float* __restrict__ W, const float* __restrict__ Wl, unsigned short* __restrict__ hi,
    unsigned short* __restrict__ lo) {
    int bx = blockIdx.x;
    if (bx < NSTRIPE) {
        __shared__ int lhist[1024];
        int t = threadIdx.x;
        for (int k = t; k < 1024; k += 256) lhist[k] = 0;
        __syncthreads();
        int base = bx * EPB + t;
#pragma unroll 4
        for (int k = 0; k < EPB / 256; k++) {
            int i = base + k * 256;
            if (i < N_EDGES) atomicAdd(&lhist[((unsigned)dst[i]) >> 6], 1);
        }
        __syncthreads();
        for (int k = t; k < NBUCK; k += 256)
            if (lhist[k]) atomicAdd(&bcnt[k], lhist[k]);
    } else {
        // weight split: [0,16384) fcW | [16384,65536) W | [65536,73728) W_last
        int i = (bx - NSTRIPE) * 256 + threadIdx.x;
        float v;
        if (i < 16384) v = fcW[i];
        else if (i < 65536) v = W[i - 16384];
        else if (i < 73728) v = Wl[i - 65536];
        else return;
        unsigned short h = f2bf(v);
        hi[i] = h;
        lo[i] = f2bf(v - bf2f(h));
    }
}

// ---------------- bucket offsets (1 block, 1024 threads) ----------------

__global__ void bucket_scan(const int* __restrict__ bcnt, int* __restrict__ boff,
                            int* __restrict__ cursor) {
    __shared__ int sm[1024];
    int t = threadIdx.x;
    int v = (t < NBUCK) ? bcnt[t] : 0;
    sm[t] = v;
    __syncthreads();
    for (int o = 1; o < 1024; o <<= 1) {
        int x = sm[t];
        int a = (t >= o) ? sm[t - o] : 0;
        __syncthreads();
        sm[t] = x + a;
        __syncthreads();
    }
    if (t < NBUCK) {
        boff[t] = sm[t] - v;
        cursor[t] = sm[t] - v;
    }
    if (t == NBUCK - 1) boff[NBUCK] = sm[t];
}

// ---------------- split-bf16 MFMA GEMM body (global A) ----------------
// D = Ahi*Whi + Alo*Whi + Ahi*Wlo (missing Alo*Wlo ~ 2^-18 rel).
// Epilogue writes split hi/lo bf16 activations (non-LAST) or fp32 (LAST).

template <int COLS, bool RELU, bool LAST>
__device__ __forceinline__ void gemm_body(int bx, const float* __restrict__ U,
                                          const unsigned short* __restrict__ Whi,
                                          const unsigned short* __restrict__ Wlo,
                                          const float* __restrict__ bias,
                                          unsigned short* __restrict__ hi_out,
                                          unsigned short* __restrict__ lo_out,
                                          float* __restrict__ out_last, int nrows) {
    int wave = threadIdx.x >> 6;
    int lane = threadIdx.x & 63;
    int m = lane & 15;
    int quad = lane >> 4;
    int r0 = bx * 64 + wave * 16;
    int rowA = r0 + m;
    if (rowA >= nrows) rowA = nrows - 1;  // clamp OOB loads (stores guarded)

    short8 ahi[4], alo[4];
    const float* arow = U + (size_t)rowA * 128 + quad * 8;
#pragma unroll
    for (int kc = 0; kc < 4; kc++) {
        float4 f0 = *(const float4*)(arow + kc * 32);
        float4 f1 = *(const float4*)(arow + kc * 32 + 4);
        float fv[8] = {f0.x, f0.y, f0.z, f0.w, f1.x, f1.y, f1.z, f1.w};
#pragma unroll
        for (int j = 0; j < 8; j++) {
            unsigned short h = f2bf(fv[j]);
            ahi[kc][j] = (short)h;
            alo[kc][j] = (short)f2bf(fv[j] - bf2f(h));
        }
    }

#pragma unroll
    for (int nt = 0; nt < COLS / 16; nt++) {
        int n = nt * 16 + m;
        const unsigned short* bhp = Whi + (size_t)n * 128 + quad * 8;
        const unsigned short* blp = Wlo + (size_t)n * 128 + quad * 8;
        float4v c = {0.f, 0.f, 0.f, 0.f};
#pragma unroll
        for (int kc = 0; kc < 4; kc++) {
            short8 bh = *(const short8*)(bhp + kc * 32);
            short8 bl = *(const short8*)(blp + kc * 32);
            c = __builtin_amdgcn_mfma_f32_16x16x32_bf16(ahi[kc], bh, c, 0, 0, 0);
            c = __builtin_amdgcn_mfma_f32_16x16x32_bf16(alo[kc], bh, c, 0, 0, 0);
            c = __builtin_amdgcn_mfma_f32_16x16x32_bf16(ahi[kc], bl, c, 0, 0, 0);
        }
        float bv = bias[n];
#pragma unroll
        for (int k = 0; k < 4; k++) {
            int r = r0 + quad * 4 + k;
            if (r < nrows) {
                float v = c[k] + bv;
                if (RELU) v = fmaxf(v, 0.f);
                if (LAST) {
                    out_last[(size_t)r * COLS + n] = v;
                } else {
                    unsigned short hh = f2bf(v);
                    hi_out[(size_t)r * COLS + n] = hh;
                    lo_out[(size_t)r * COLS + n] = f2bf(v - bf2f(hh));
                }
            }
        }
    }
}

// ---------------- fused: pass A binning (196 blocks) + SLP GEMM (782) ----------

__global__ void __launch_bounds__(256) fused_binA_gemm(
    const int* __restrict__ src, const int* __restrict__ dst, int* __restrict__ cursor,
    int* __restrict__ packed, const float* __restrict__ X, const unsigned short* __restrict__ whi,
    const unsigned short* __restrict__ wlo, const float* __restrict__ fcb,
    unsigned short* __restrict__ hi_out, unsigned short* __restrict__ lo_out) {
    int bx = blockIdx.x;
    if (bx < NSTRIPE) {
        __shared__ int lcount[1024];
        __shared__ int lbase[1024];
        int t = threadIdx.x;
        for (int k = t; k < 1024; k += 256) lcount[k] = 0;
        __syncthreads();
        int base = bx * EPB + t;
#pragma unroll 4
        for (int k = 0; k < EPB / 256; k++) {
            int i = base + k * 256;
            if (i < N_EDGES) atomicAdd(&lcount[((unsigned)dst[i]) >> 6], 1);
        }
        __syncthreads();
        for (int k = t; k < NBUCK; k += 256) {
            int c = lcount[k];
            lbase[k] = c ? atomicAdd(&cursor[k], c) : 0;
            lcount[k] = 0;
        }
        __syncthreads();
#pragma unroll 4
        for (int k = 0; k < EPB / 256; k++) {
            int i = base + k * 256;
            if (i < N_EDGES) {
                int d = dst[i];
                int wb = ((unsigned)d) >> 6;
                int p = lbase[wb] + atomicAdd(&lcount[wb], 1);
                packed[p] = ((d & 63) << 16) | src[i];
            }
        }
    } else {
        gemm_body<128, true, false>(bx - NSTRIPE, X, whi, wlo, fcb, hi_out, lo_out, nullptr,
                                    N_NODES);
    }
}

// ---------------- per-node 1/deg (once; reused all 4 layers) ----------------

__global__ void __launch_bounds__(256) inv_kernel(const int* __restrict__ packed,
                                                  const int* __restrict__ boff,
                                                  float* __restrict__ inv) {
    __shared__ int dh[BKN];
    int b = blockIdx.x, t = threadIdx.x;
    if (t < BKN) dh[t] = 0;
    __syncthreads();
    int e0 = boff[b], e1 = boff[b + 1];
    for (int i = e0 + t; i < e1; i += 256) atomicAdd(&dh[((unsigned)packed[i]) >> 16], 1);
    __syncthreads();
    if (t < BKN) {
        int node = b * BKN + t;
        if (node < N_NODES) inv[node] = dh[t] ? 1.0f / (float)dh[t] : 0.0f;
    }
}

// ---------------- fused GIN layer: LDS agg + self-term + MFMA GEMM ----------------
// One block per 64-node bucket. Gather: wave per edge, coalesced 256B bf16 row,
// fire-and-forget ds_add_f32 into acc. Then u=(1+eps)*(hi+lo)+acc*inv in LDS,
// then MFMA from LDS A. u never touches global.

template <int COLS, bool RELU, bool LAST>
__global__ void __launch_bounds__(256, 4) fused_layer(
    const unsigned short* __restrict__ hi_prev, const unsigned short* __restrict__ lo_prev,
    const int* __restrict__ packed, const int* __restrict__ boff, const float* __restrict__ inv,
    const float* __restrict__ eps, int layer, const unsigned short* __restrict__ Whi,
    const unsigned short* __restrict__ Wlo, const float* __restrict__ bias,
    unsigned short* __restrict__ hi_out, unsigned short* __restrict__ lo_out,
    float* __restrict__ out_last) {
    __shared__ float acc[BKN * ASTR];  // 33792 B
    int b = blockIdx.x;
    int t = threadIdx.x;
    int wv = t >> 6, lane = t & 63;
    int node0 = b * BKN;

    for (int i = t; i < BKN * ASTR; i += 256) acc[i] = 0.f;
    __syncthreads();

    // ---- gather: mean-sum neighbors into LDS ----
    int e0 = boff[b], e1 = boff[b + 1];
    int cnt = e1 - e0;
    int chunk = (cnt + 3) >> 2;
    int s = e0 + wv * chunk;
    int epnd = s + chunk;
    if (epnd > e1) epnd = e1;
    int i = s;
    for (; i + 3 < epnd; i += 4) {
        int w0 = packed[i], w1 = packed[i + 1], w2 = packed[i + 2], w3 = packed[i + 3];
        unsigned v0 = *((const unsigned*)(hi_prev + ((size_t)(w0 & 0xFFFF)) * 128) + lane);
        unsigned v1 = *((const unsigned*)(hi_prev + ((size_t)(w1 & 0xFFFF)) * 128) + lane);
        unsigned v2 = *((const unsigned*)(hi_prev + ((size_t)(w2 & 0xFFFF)) * 128) + lane);
        unsigned v3 = *((const unsigned*)(hi_prev + ((size_t)(w3 & 0xFFFF)) * 128) + lane);
        float* a0 = acc + (w0 >> 16) * ASTR + lane * 2;
        float* a1 = acc + (w1 >> 16) * ASTR + lane * 2;
        float* a2 = acc + (w2 >> 16) * ASTR + lane * 2;
        float* a3 = acc + (w3 >> 16) * ASTR + lane * 2;
        atomicAdd(a0, bf2f((unsigned short)v0));
        atomicAdd(a0 + 1, bf2f((unsigned short)(v0 >> 16)));
        atomicAdd(a1, bf2f((unsigned short)v1));
        atomicAdd(a1 + 1, bf2f((unsigned short)(v1 >> 16)));
        atomicAdd(a2, bf2f((unsigned short)v2));
        atomicAdd(a2 + 1, bf2f((unsigned short)(v2 >> 16)));
        atomicAdd(a3, bf2f((unsigned short)v3));
        atomicAdd(a3 + 1, bf2f((unsigned short)(v3 >> 16)));
    }
    for (; i < epnd; i++) {
        int w = packed[i];
        unsigned v = *((const unsigned*)(hi_prev + ((size_t)(w & 0xFFFF)) * 128) + lane);
        float* a = acc + (w >> 16) * ASTR + lane * 2;
        atomicAdd(a, bf2f((unsigned short)v));
        atomicAdd(a + 1, bf2f((unsigned short)(v >> 16)));
    }
    __syncthreads();

    // ---- self-term + normalize: u = (1+eps)*(hi+lo) + acc*inv ----
    float ep = 1.0f + eps[layer];
    for (int g = t; g < BKN * 32; g += 256) {
        int row = g >> 5;
        int col = (g & 31) << 2;
        int node = node0 + row;
        if (node < N_NODES) {
            float iv = inv[node];
            const unsigned short* hp = hi_prev + (size_t)node * 128 + col;
            const unsigned short* lp = lo_prev + (size_t)node * 128 + col;
            float* ap = acc + row * ASTR + col;
#pragma unroll
            for (int k = 0; k < 4; k++) {
                float self = bf2f(hp[k]) + bf2f(lp[k]);
                ap[k] = ep * self + ap[k] * iv;
            }
        }
    }
    __syncthreads();

    // ---- GEMM from LDS A (split bf16, 3-product) ----
    int m = lane & 15, quad = lane >> 4;
    int lr0 = wv * 16;
    short8 ahi[4], alo[4];
    const float* ar = acc + (lr0 + m) * ASTR + quad * 8;
#pragma unroll
    for (int kc = 0; kc < 4; kc++) {
        float4 f0 = *(const float4*)(ar + kc * 32);
        float4 f1 = *(const float4*)(ar + kc * 32 + 4);
        float fv[8] = {f0.x, f0.y, f0.z, f0.w, f1.x, f1.y, f1.z, f1.w};
#pragma unroll
        for (int j = 0; j < 8; j++) {
            unsigned short hh = f2bf(fv[j]);
            ahi[kc][j] = (short)hh;
            alo[kc][j] = (short)f2bf(fv[j] - bf2f(hh));
        }
    }
#pragma unroll
    for (int nt = 0; nt < COLS / 16; nt++) {
        int n = nt * 16 + m;
        const unsigned short* bhp = Whi + (size_t)n * 128 + quad * 8;
        const unsigned short* blp = Wlo + (size_t)n * 128 + quad * 8;
        float4v c = {0.f, 0.f, 0.f, 0.f};
#pragma unroll
        for (int kc = 0; kc < 4; kc++) {
            short8 bh = *(const short8*)(bhp + kc * 32);
            short8 bl = *(const short8*)(blp + kc * 32);
            c = __builtin_amdgcn_mfma_f32_16x16x32_bf16(ahi[kc], bh, c, 0, 0, 0);
            c = __builtin_amdgcn_mfma_f32_16x16x32_bf16(alo[kc], bh, c, 0, 0, 0);
            c = __builtin_amdgcn_mfma_f32_16x16x32_bf16(ahi[kc], bl, c, 0, 0, 0);
        }
        float bv = bias[n];
#pragma unroll
        for (int k = 0; k < 4; k++) {
            int node = node0 + lr0 + quad * 4 + k;
            if (node < N_NODES) {
                float v = c[k] + bv;
                if (RELU) v = fmaxf(v, 0.f);
                if (LAST) {
                    out_last[(size_t)node * COLS + n] = v;
                } else {
                    unsigned short hh = f2bf(v);
                    hi_out[(size_t)node * COLS + n] = hh;
                    lo_out[(size_t)node * COLS + n] = f2bf(v - bf2f(hh));
                }
            }
        }
    }
}

// ---------------- launch ----------------

extern "C" void kernel_launch(void* const* d_in, const int* in_sizes, int n_in,
                              void* d_out, int out_size, void* d_ws, size_t ws_size,
                              hipStream_t stream) {
    const float* X   = (const float*)d_in[0];
    const float* fcW = (const float*)d_in[1];
    const float* fcb = (const float*)d_in[2];
    const float* W   = (const float*)d_in[3];
    const float* b   = (const float*)d_in[4];
    const float* Wl  = (const float*)d_in[5];
    const float* bl  = (const float*)d_in[6];
    const float* eps = (const float*)d_in[7];
    const int* src   = (const int*)d_in[8];
    const int* dst   = (const int*)d_in[9];
    float* out = (float*)d_out;

    // workspace carve (~55 MB)
    const size_t NF = (size_t)N_NODES * 128;
    unsigned short* hi_a = (unsigned short*)d_ws;         // NF bf16
    unsigned short* lo_a = hi_a + NF;
    unsigned short* hi_b = lo_a + NF;
    unsigned short* lo_b = hi_b + NF;
    unsigned short* whi  = lo_b + NF;                     // 73728
    unsigned short* wlo  = whi + 73728;                   // 73728
    float* inv   = (float*)(wlo + 73728);                 // N_NODES
    int* bcnt    = (int*)(inv + N_NODES);                 // 1024
    int* boff    = bcnt + 1024;                           // NBUCK+1
    int* cursor  = boff + NBUCK + 1;                      // NBUCK
    int* packed  = cursor + NBUCK;                        // N_EDGES

    const int gemm_blocks = (N_NODES + 63) / 64;        // 782
    const int prep_blocks = (73728 + 255) / 256;        // 288

    hipMemsetAsync(bcnt, 0, 1024 * sizeof(int), stream);
    fused_hist_prep<<<NSTRIPE + prep_blocks, 256, 0, stream>>>(dst, bcnt, fcW, W, Wl, whi, wlo);
    bucket_scan<<<1, 1024, 0, stream>>>(bcnt, boff, cursor);
    fused_binA_gemm<<<NSTRIPE + gemm_blocks, 256, 0, stream>>>(src, dst, cursor, packed, X, whi,
                                                               wlo, fcb, hi_a, lo_a);
    inv_kernel<<<NBUCK, 256, 0, stream>>>(packed, boff, inv);

    // 3 hidden GIN layers (a->b->a->b), then last layer -> d_out
    fused_layer<128, true, false><<<NBUCK, 256, 0, stream>>>(
        hi_a, lo_a, packed, boff, inv, eps, 0, whi + 16384, wlo + 16384, b, hi_b, lo_b, nullptr);
    fused_layer<128, true, false><<<NBUCK, 256, 0, stream>>>(
        hi_b, lo_b, packed, boff, inv, eps, 1, whi + 32768, wlo + 32768, b + 128, hi_a, lo_a,
        nullptr);
    fused_layer<128, true, false><<<NBUCK, 256, 0, stream>>>(
        hi_a, lo_a, packed, boff, inv, eps, 2, whi + 49152, wlo + 49152, b + 256, hi_b, lo_b,
        nullptr);
    fused_layer<64, false, true><<<NBUCK, 256, 0, stream>>>(
        hi_b, lo_b, packed, boff, inv, eps, 3, whi + 65536, wlo + 65536, bl, nullptr, nullptr,
        out);
}